// Round 1
// baseline (2694.076 us; speedup 1.0000x reference)
//
#include <hip/hip_runtime.h>
#include <math.h>

#define LN2F 0.6931471805599453f

__device__ __forceinline__ float sspf(float z) {
    // ssp(z) = softplus(z) - ln2, numerically stable
    float az = fabsf(z);
    return fmaxf(z, 0.0f) + log1pf(__expf(-az)) - LN2F;
}

// C = act(A @ B + bias); A:[nrows,128], B:[128,128], C:[nrows,128]
// act: 0 = identity, 1 = ssp
__global__ __launch_bounds__(256) void gemm_tile(
    const float* __restrict__ A, const float* __restrict__ B,
    const float* __restrict__ bias, float* __restrict__ C,
    int nrows, int act)
{
    __shared__ float As[64][132];   // padded: +4 floats/row (16B-aligned rows, bank shift)
    __shared__ float Bs[32][128];

    const int tid = threadIdx.x;
    const int r0  = blockIdx.x * 64;

    // stage A tile (64x128) as float4, zero-fill OOB rows
    #pragma unroll
    for (int t = 0; t < 8; ++t) {
        int idx = tid + t * 256;          // float4 index
        int r = idx >> 5;                 // 32 float4 per row
        int c = (idx & 31) << 2;
        float4 v = make_float4(0.f, 0.f, 0.f, 0.f);
        if (r0 + r < nrows) v = *(const float4*)(A + (size_t)(r0 + r) * 128 + c);
        *(float4*)&As[r][c] = v;
    }

    const int rg = tid >> 4;      // 0..15 -> rows rg*4..rg*4+3
    const int cg = tid & 15;      // 0..15 -> cols cg*8..cg*8+7
    const int f0 = cg * 8;

    float acc[4][8];
    #pragma unroll
    for (int i = 0; i < 4; ++i)
        #pragma unroll
        for (int j = 0; j < 8; ++j) acc[i][j] = 0.f;

    for (int kb = 0; kb < 128; kb += 32) {
        __syncthreads();
        #pragma unroll
        for (int t = 0; t < 4; ++t) {
            int idx = tid + t * 256;
            ((float4*)Bs)[idx] = ((const float4*)(B + (size_t)kb * 128))[idx];
        }
        __syncthreads();
        #pragma unroll 8
        for (int kk = 0; kk < 32; ++kk) {
            float a0 = As[rg * 4 + 0][kb + kk];
            float a1 = As[rg * 4 + 1][kb + kk];
            float a2 = As[rg * 4 + 2][kb + kk];
            float a3 = As[rg * 4 + 3][kb + kk];
            float4 bl = *(const float4*)&Bs[kk][f0];
            float4 bh = *(const float4*)&Bs[kk][f0 + 4];
            float b[8] = {bl.x, bl.y, bl.z, bl.w, bh.x, bh.y, bh.z, bh.w};
            #pragma unroll
            for (int j = 0; j < 8; ++j) {
                acc[0][j] = fmaf(a0, b[j], acc[0][j]);
                acc[1][j] = fmaf(a1, b[j], acc[1][j]);
                acc[2][j] = fmaf(a2, b[j], acc[2][j]);
                acc[3][j] = fmaf(a3, b[j], acc[3][j]);
            }
        }
    }

    float bv[8];
    if (bias) {
        float4 xl = *(const float4*)(bias + f0);
        float4 xh = *(const float4*)(bias + f0 + 4);
        bv[0]=xl.x; bv[1]=xl.y; bv[2]=xl.z; bv[3]=xl.w;
        bv[4]=xh.x; bv[5]=xh.y; bv[6]=xh.z; bv[7]=xh.w;
    } else {
        #pragma unroll
        for (int j = 0; j < 8; ++j) bv[j] = 0.f;
    }

    #pragma unroll
    for (int i = 0; i < 4; ++i) {
        int r = r0 + rg * 4 + i;
        if (r < nrows) {
            float o[8];
            #pragma unroll
            for (int j = 0; j < 8; ++j) {
                float v = acc[i][j] + bv[j];
                o[j] = act ? sspf(v) : v;
            }
            *(float4*)(C + (size_t)r * 128 + f0)     = make_float4(o[0], o[1], o[2], o[3]);
            *(float4*)(C + (size_t)r * 128 + f0 + 4) = make_float4(o[4], o[5], o[6], o[7]);
        }
    }
}

// Fused edge kernel: per 64-edge tile
//   w1  = ssp(f_ij @ W_f1 + b_f1)            [64,128]
//   Wij = (w1 @ W_f2 + b_f2) * rcut          [64,128]
//   x_ij = h[idx_j] * Wij
//   agg[idx_i] += x_ij   (segmented: idx_i sorted -> per-thread run merge + atomics)
__global__ __launch_bounds__(256) void edge_kernel(
    const float* __restrict__ f_ij, const float* __restrict__ rcut,
    const int* __restrict__ idx_i, const int* __restrict__ idx_j,
    const float* __restrict__ Wf1, const float* __restrict__ bf1,
    const float* __restrict__ Wf2, const float* __restrict__ bf2,
    const float* __restrict__ h, float* __restrict__ agg, int E)
{
    __shared__ float w1s[64][132];     // 33792 B (padded)
    __shared__ float Bs[32][128];      // 16384 B (reused: W_f1 stage, then W_f2 chunks)
    __shared__ float fijs[64][20];     //  5120 B
    __shared__ int   iis[64];

    const int tid = threadIdx.x;
    const int e0  = blockIdx.x * 64;

    // stage f_ij tile (64 x 20), coalesced
    for (int idx = tid; idx < 64 * 20; idx += 256) {
        int e = idx / 20, r = idx % 20;
        float v = 0.f;
        if (e0 + e < E) v = f_ij[(size_t)(e0) * 20 + idx];
        fijs[e][r] = v;
    }
    // stage W_f1 (20 x 128) into Bs
    float* wf1s = (float*)Bs;
    for (int idx = tid; idx < 20 * 128; idx += 256) wf1s[idx] = Wf1[idx];
    if (tid < 64) iis[tid] = (e0 + tid < E) ? idx_i[e0 + tid] : 0;
    __syncthreads();

    // phase 2: w1 = ssp(f_ij @ W_f1 + b_f1)
    {
        const int f  = tid & 127;
        const int eh = tid >> 7;
        const float bb = bf1[f];
        for (int e = eh; e < 64; e += 2) {
            float a = bb;
            #pragma unroll
            for (int r = 0; r < 20; ++r) a = fmaf(fijs[e][r], wf1s[r * 128 + f], a);
            w1s[e][f] = sspf(a);
        }
    }

    const int rg = tid >> 4;
    const int cg = tid & 15;
    const int f0 = cg * 8;

    float acc[4][8];
    #pragma unroll
    for (int i = 0; i < 4; ++i)
        #pragma unroll
        for (int j = 0; j < 8; ++j) acc[i][j] = 0.f;

    // phase 3: Wij-pre = w1 @ W_f2
    for (int kb = 0; kb < 128; kb += 32) {
        __syncthreads();   // protects Bs reuse and chunk swap
        #pragma unroll
        for (int t = 0; t < 4; ++t) {
            int idx = tid + t * 256;
            ((float4*)Bs)[idx] = ((const float4*)(Wf2 + (size_t)kb * 128))[idx];
        }
        __syncthreads();
        #pragma unroll 8
        for (int kk = 0; kk < 32; ++kk) {
            float a0 = w1s[rg * 4 + 0][kb + kk];
            float a1 = w1s[rg * 4 + 1][kb + kk];
            float a2 = w1s[rg * 4 + 2][kb + kk];
            float a3 = w1s[rg * 4 + 3][kb + kk];
            float4 bl = *(const float4*)&Bs[kk][f0];
            float4 bh = *(const float4*)&Bs[kk][f0 + 4];
            float b[8] = {bl.x, bl.y, bl.z, bl.w, bh.x, bh.y, bh.z, bh.w};
            #pragma unroll
            for (int j = 0; j < 8; ++j) {
                acc[0][j] = fmaf(a0, b[j], acc[0][j]);
                acc[1][j] = fmaf(a1, b[j], acc[1][j]);
                acc[2][j] = fmaf(a2, b[j], acc[2][j]);
                acc[3][j] = fmaf(a3, b[j], acc[3][j]);
            }
        }
    }

    // epilogue: (+b_f2) * rcut * h[idx_j], then segmented scatter-add
    float4 b2l = *(const float4*)(bf2 + f0);
    float4 b2h = *(const float4*)(bf2 + f0 + 4);
    float bb2[8] = {b2l.x, b2l.y, b2l.z, b2l.w, b2h.x, b2h.y, b2h.z, b2h.w};

    int eat[4];
    #pragma unroll
    for (int i = 0; i < 4; ++i) {
        int e = rg * 4 + i;
        int ge = e0 + e;
        bool ok = ge < E;
        float rc = ok ? rcut[ge] : 0.f;
        int ja = ok ? idx_j[ge] : 0;
        eat[i] = iis[e];
        const float* hrow = h + (size_t)ja * 128 + f0;
        float4 h0 = *(const float4*)hrow;
        float4 h1 = *(const float4*)(hrow + 4);
        float hv[8] = {h0.x, h0.y, h0.z, h0.w, h1.x, h1.y, h1.z, h1.w};
        #pragma unroll
        for (int j = 0; j < 8; ++j)
            acc[i][j] = (acc[i][j] + bb2[j]) * rc * hv[j];
    }

    float run[8];
    int cur = eat[0];
    #pragma unroll
    for (int j = 0; j < 8; ++j) run[j] = acc[0][j];
    #pragma unroll
    for (int i = 1; i < 4; ++i) {
        if (eat[i] == cur) {
            #pragma unroll
            for (int j = 0; j < 8; ++j) run[j] += acc[i][j];
        } else {
            float* dst = agg + (size_t)cur * 128 + f0;
            #pragma unroll
            for (int j = 0; j < 8; ++j) atomicAdd(dst + j, run[j]);
            cur = eat[i];
            #pragma unroll
            for (int j = 0; j < 8; ++j) run[j] = acc[i][j];
        }
    }
    {
        float* dst = agg + (size_t)cur * 128 + f0;
        #pragma unroll
        for (int j = 0; j < 8; ++j) atomicAdd(dst + j, run[j]);
    }
}

extern "C" void kernel_launch(void* const* d_in, const int* in_sizes, int n_in,
                              void* d_out, int out_size, void* d_ws, size_t ws_size,
                              hipStream_t stream)
{
    const float* x      = (const float*)d_in[0];
    const float* f_ij   = (const float*)d_in[1];
    const float* rcut   = (const float*)d_in[2];
    const int*   idx_i  = (const int*)d_in[3];
    const int*   idx_j  = (const int*)d_in[4];
    const float* W_in2f = (const float*)d_in[5];
    const float* W_f1   = (const float*)d_in[6];
    const float* b_f1   = (const float*)d_in[7];
    const float* W_f2   = (const float*)d_in[8];
    const float* b_f2   = (const float*)d_in[9];
    const float* W_o1   = (const float*)d_in[10];
    const float* b_o1   = (const float*)d_in[11];
    const float* W_o2   = (const float*)d_in[12];
    const float* b_o2   = (const float*)d_in[13];

    const int N = in_sizes[0] / 128;
    const int E = in_sizes[2];

    float* hbuf = (float*)d_ws;       // [N,128]; reused as t-buffer for out-MLP
    float* agg  = (float*)d_out;      // [N,128] accumulator lives in d_out

    // zero agg (atomics accumulate into it)
    hipMemsetAsync(d_out, 0, (size_t)N * 128 * sizeof(float), stream);

    const int gn = (N + 63) / 64;
    const int ge = (E + 63) / 64;

    // h = x @ W_in2f
    gemm_tile<<<gn, 256, 0, stream>>>(x, W_in2f, nullptr, hbuf, N, 0);

    // fused edge pipeline -> agg (in d_out)
    edge_kernel<<<ge, 256, 0, stream>>>(f_ij, rcut, idx_i, idx_j,
                                        W_f1, b_f1, W_f2, b_f2, hbuf, agg, E);

    // t = ssp(agg @ W_o1 + b_o1)   (t overwrites hbuf; h no longer needed)
    gemm_tile<<<gn, 256, 0, stream>>>(agg, W_o1, b_o1, hbuf, N, 1);

    // out = t @ W_o2 + b_o2
    gemm_tile<<<gn, 256, 0, stream>>>(hbuf, W_o2, b_o2, (float*)d_out, N, 0);
}

// Round 2
// 1174.288 us; speedup vs baseline: 2.2942x; 2.2942x over previous
//
#include <hip/hip_runtime.h>
#include <math.h>

#define LN2F 0.6931471805599453f

typedef _Float16 half_t;
typedef _Float16 half4_t __attribute__((ext_vector_type(4)));
typedef float f32x4 __attribute__((ext_vector_type(4)));

__device__ __forceinline__ float sspf(float z) {
    // ssp(z) = softplus(z) - ln2, numerically stable
    float az = fabsf(z);
    return fmaxf(z, 0.0f) + log1pf(__expf(-az)) - LN2F;
}

__device__ __forceinline__ half4_t cvt4(float x, float y, float z, float w) {
    half4_t r; r[0] = (half_t)x; r[1] = (half_t)y; r[2] = (half_t)z; r[3] = (half_t)w;
    return r;
}

__device__ __forceinline__ int lbound(const int* __restrict__ a, int n, int key) {
    int lo = 0, hi = n;
    while (lo < hi) { int m = (lo + hi) >> 1; if (a[m] < key) lo = m + 1; else hi = m; }
    return lo;
}

// dst[n*Kp + k] = (k < K) ? src[k*128 + n] : 0   (f32 -> f16, transpose, K-pad)
__global__ __launch_bounds__(256) void transpose_cvt(
    const float* __restrict__ src, half_t* __restrict__ dst, int K, int Kp)
{
    int i = blockIdx.x * 256 + threadIdx.x;
    if (i >= 128 * Kp) return;
    int n = i / Kp, k = i % Kp;
    dst[i] = (k < K) ? (half_t)src[k * 128 + n] : (half_t)0.f;
}

// C = act(A @ B + bias); A:[nrows,128] f32, Bt:[128][128] f16 (Bt[n][k]=B[k][n])
// block: 64 rows x 128 cols, 4 waves; wave w owns cols [32w, 32w+32), all 64 rows.
__global__ __launch_bounds__(256) void mfma_gemm(
    const float* __restrict__ A, const half_t* __restrict__ Bt,
    const float* __restrict__ bias, float* __restrict__ C,
    int nrows, int act)
{
    const int tid = threadIdx.x;
    const int w = tid >> 6, l = tid & 63, g = l >> 4, ln = l & 15;
    const int r0 = blockIdx.x * 64;

    f32x4 acc[4][2];
    #pragma unroll
    for (int rf = 0; rf < 4; ++rf)
        #pragma unroll
        for (int cf = 0; cf < 2; ++cf) acc[rf][cf] = (f32x4)0.f;

    #pragma unroll
    for (int kk = 0; kk < 8; ++kk) {
        const int kb = kk * 16 + g * 4;
        half4_t a[4];
        #pragma unroll
        for (int rf = 0; rf < 4; ++rf) {
            int r = r0 + rf * 16 + ln;
            int rr = r < nrows ? r : nrows - 1;   // clamp (value unused if OOB)
            float4 av = *(const float4*)(A + (size_t)rr * 128 + kb);
            a[rf] = cvt4(av.x, av.y, av.z, av.w);
        }
        #pragma unroll
        for (int cf = 0; cf < 2; ++cf) {
            int n = w * 32 + cf * 16 + ln;
            half4_t b = *(const half4_t*)(Bt + (size_t)n * 128 + kb);
            #pragma unroll
            for (int rf = 0; rf < 4; ++rf)
                acc[rf][cf] = __builtin_amdgcn_mfma_f32_16x16x16f16(a[rf], b, acc[rf][cf], 0, 0, 0);
        }
    }

    #pragma unroll
    for (int cf = 0; cf < 2; ++cf) {
        int n = w * 32 + cf * 16 + ln;
        float bv = bias ? bias[n] : 0.f;
        #pragma unroll
        for (int rf = 0; rf < 4; ++rf) {
            #pragma unroll
            for (int reg = 0; reg < 4; ++reg) {
                int r = r0 + rf * 16 + g * 4 + reg;
                if (r < nrows) {
                    float v = acc[rf][cf][reg] + bv;
                    C[(size_t)r * 128 + n] = act ? sspf(v) : v;
                }
            }
        }
    }
}

// Fused edge pipeline, one block per 4 consecutive atoms (idx_i sorted).
//   w1  = ssp(f_ij @ W_f1 + b_f1)   (MFMA, K=32 padded)
//   Wij = (w1 @ W_f2 + b_f2) * rcut (MFMA, K=128)
//   x_ij = h[idx_j] * Wij ; bins[idx_i] += x_ij (LDS, run-merged) ; plain stores
__global__ __launch_bounds__(256) void edge_kernel(
    const float* __restrict__ f_ij, const float* __restrict__ rcut,
    const int* __restrict__ idx_i, const int* __restrict__ idx_j,
    const half_t* __restrict__ Wt_f1, const float* __restrict__ b_f1,
    const half_t* __restrict__ Wt_f2, const float* __restrict__ b_f2,
    const float* __restrict__ h, float* __restrict__ agg, int E, int N)
{
    __shared__ half_t w1s[64][136];     // 17408 B, +8 halfs pad per row
    __shared__ float  bins[4][128];     //  2048 B

    const int tid = threadIdx.x;
    const int w = tid >> 6, l = tid & 63, g = l >> 4, ln = l & 15;
    const int a0 = blockIdx.x * 4;

    for (int i = tid; i < 512; i += 256) ((float*)bins)[i] = 0.f;

    const int lo = lbound(idx_i, E, a0);
    const int hi = lbound(idx_i, E, a0 + 4);
    __syncthreads();

    const int n0 = w * 32 + ln;   // cf=0 column
    const int n1 = n0 + 16;       // cf=1 column
    const float bf1v0 = b_f1[n0], bf1v1 = b_f1[n1];
    const float bf2v0 = b_f2[n0], bf2v1 = b_f2[n1];

    float aggr0 = 0.f, aggr1 = 0.f;
    int cur = -1;

    for (int c0 = lo; c0 < hi; c0 += 64) {
        // ---- phase 1: z = f_ij @ Wt_f1  (K padded to 32) ----
        f32x4 z[4][2];
        #pragma unroll
        for (int rf = 0; rf < 4; ++rf)
            #pragma unroll
            for (int cf = 0; cf < 2; ++cf) z[rf][cf] = (f32x4)0.f;

        #pragma unroll
        for (int kk = 0; kk < 2; ++kk) {
            const int kb = kk * 16 + g * 4;
            half4_t a[4];
            #pragma unroll
            for (int rf = 0; rf < 4; ++rf) {
                int e = c0 + rf * 16 + ln;
                half4_t av = (half4_t)(half_t)0.f;
                if (e < hi && kb < 20) {   // row 80B: offsets {0,16,32,48,64} all 16B-aligned
                    float4 fv = *(const float4*)(f_ij + (size_t)e * 20 + kb);
                    av = cvt4(fv.x, fv.y, fv.z, fv.w);
                }
                a[rf] = av;
            }
            #pragma unroll
            for (int cf = 0; cf < 2; ++cf) {
                half4_t b = *(const half4_t*)(Wt_f1 + (size_t)(n0 + cf * 16) * 32 + kb);
                #pragma unroll
                for (int rf = 0; rf < 4; ++rf)
                    z[rf][cf] = __builtin_amdgcn_mfma_f32_16x16x16f16(a[rf], b, z[rf][cf], 0, 0, 0);
            }
        }

        // w1 = ssp(z + b_f1) -> LDS (this wave's 32-col slice, all 64 rows)
        #pragma unroll
        for (int rf = 0; rf < 4; ++rf)
            #pragma unroll
            for (int reg = 0; reg < 4; ++reg) {
                int r = rf * 16 + g * 4 + reg;
                w1s[r][n0] = (half_t)sspf(z[rf][0][reg] + bf1v0);
                w1s[r][n1] = (half_t)sspf(z[rf][1][reg] + bf1v1);
            }
        __syncthreads();

        // ---- phase 2: acc = w1 @ Wt_f2 (K=128) ----
        f32x4 acc[4][2];
        #pragma unroll
        for (int rf = 0; rf < 4; ++rf)
            #pragma unroll
            for (int cf = 0; cf < 2; ++cf) acc[rf][cf] = (f32x4)0.f;

        #pragma unroll
        for (int kk = 0; kk < 8; ++kk) {
            const int kb = kk * 16 + g * 4;
            half4_t a[4];
            #pragma unroll
            for (int rf = 0; rf < 4; ++rf)
                a[rf] = *(const half4_t*)&w1s[rf * 16 + ln][kb];
            #pragma unroll
            for (int cf = 0; cf < 2; ++cf) {
                half4_t b = *(const half4_t*)(Wt_f2 + (size_t)(n0 + cf * 16) * 128 + kb);
                #pragma unroll
                for (int rf = 0; rf < 4; ++rf)
                    acc[rf][cf] = __builtin_amdgcn_mfma_f32_16x16x16f16(a[rf], b, acc[rf][cf], 0, 0, 0);
            }
        }
        __syncthreads();   // w1s reads complete before next chunk overwrites

        // ---- epilogue: (+b_f2)*rcut*h[idx_j], run-merged LDS binning ----
        #pragma unroll
        for (int rf = 0; rf < 4; ++rf) {
            #pragma unroll
            for (int reg = 0; reg < 4; ++reg) {
                int e = c0 + rf * 16 + g * 4 + reg;
                bool val = e < hi;
                float rc = val ? rcut[e] : 0.f;
                int   ji = val ? idx_j[e] : 0;
                int   ai = val ? idx_i[e] : a0;
                float h0 = h[(size_t)ji * 128 + n0];
                float h1 = h[(size_t)ji * 128 + n1];
                float v0 = (acc[rf][0][reg] + bf2v0) * rc * h0;
                float v1 = (acc[rf][1][reg] + bf2v1) * rc * h1;
                if (ai != cur) {
                    if (cur >= 0) {
                        atomicAdd(&bins[cur - a0][n0], aggr0);
                        atomicAdd(&bins[cur - a0][n1], aggr1);
                    }
                    cur = ai; aggr0 = v0; aggr1 = v1;
                } else {
                    aggr0 += v0; aggr1 += v1;
                }
            }
        }
    }
    if (cur >= 0) {
        atomicAdd(&bins[cur - a0][n0], aggr0);
        atomicAdd(&bins[cur - a0][n1], aggr1);
    }
    __syncthreads();

    for (int i = tid; i < 512; i += 256) {
        int at = i >> 7, n = i & 127;
        int arow = a0 + at;
        if (arow < N) agg[(size_t)arow * 128 + n] = bins[at][n];
    }
}

extern "C" void kernel_launch(void* const* d_in, const int* in_sizes, int n_in,
                              void* d_out, int out_size, void* d_ws, size_t ws_size,
                              hipStream_t stream)
{
    const float* x      = (const float*)d_in[0];
    const float* f_ij   = (const float*)d_in[1];
    const float* rcut   = (const float*)d_in[2];
    const int*   idx_i  = (const int*)d_in[3];
    const int*   idx_j  = (const int*)d_in[4];
    const float* W_in2f = (const float*)d_in[5];
    const float* W_f1   = (const float*)d_in[6];
    const float* b_f1   = (const float*)d_in[7];
    const float* W_f2   = (const float*)d_in[8];
    const float* b_f2   = (const float*)d_in[9];
    const float* W_o1   = (const float*)d_in[10];
    const float* b_o1   = (const float*)d_in[11];
    const float* W_o2   = (const float*)d_in[12];
    const float* b_o2   = (const float*)d_in[13];

    const int N = in_sizes[0] / 128;
    const int E = in_sizes[2];

    float*  hbuf = (float*)d_ws;                                   // [N,128] f32; reused as t
    half_t* wt   = (half_t*)((char*)d_ws + (size_t)N * 128 * 4);
    half_t* Wt_in2f = wt;                 // 128*128
    half_t* Wt_f1   = wt + 16384;         // 128*32 (K padded 20->32)
    half_t* Wt_f2   = wt + 16384 + 4096;  // 128*128
    half_t* Wt_o1   = Wt_f2 + 16384;      // 128*128
    half_t* Wt_o2   = Wt_o1 + 16384;      // 128*128

    // weight prep: f32 -> f16 transposed Bt[n][k]
    transpose_cvt<<<64, 256, 0, stream>>>(W_in2f, Wt_in2f, 128, 128);
    transpose_cvt<<<16, 256, 0, stream>>>(W_f1,   Wt_f1,    20,  32);
    transpose_cvt<<<64, 256, 0, stream>>>(W_f2,   Wt_f2,   128, 128);
    transpose_cvt<<<64, 256, 0, stream>>>(W_o1,   Wt_o1,   128, 128);
    transpose_cvt<<<64, 256, 0, stream>>>(W_o2,   Wt_o2,   128, 128);

    const int gn = (N + 63) / 64;
    const int ga = (N + 3) / 4;

    // h = x @ W_in2f
    mfma_gemm<<<gn, 256, 0, stream>>>(x, Wt_in2f, nullptr, hbuf, N, 0);

    // edge pipeline -> agg (plain stores into d_out, no global atomics)
    edge_kernel<<<ga, 256, 0, stream>>>(f_ij, rcut, idx_i, idx_j,
                                        Wt_f1, b_f1, Wt_f2, b_f2,
                                        hbuf, (float*)d_out, E, N);

    // t = ssp(agg @ W_o1 + b_o1)   (t overwrites hbuf; h dead)
    mfma_gemm<<<gn, 256, 0, stream>>>((const float*)d_out, Wt_o1, b_o1, hbuf, N, 1);

    // out = t @ W_o2 + b_o2
    mfma_gemm<<<gn, 256, 0, stream>>>(hbuf, Wt_o2, b_o2, (float*)d_out, N, 0);
}

// Round 3
// 594.640 us; speedup vs baseline: 4.5306x; 1.9748x over previous
//
#include <hip/hip_runtime.h>
#include <math.h>

#define LN2F 0.6931471805599453f
#define AT 8

typedef _Float16 half_t;
typedef _Float16 half4_t __attribute__((ext_vector_type(4)));
typedef float f32x4 __attribute__((ext_vector_type(4)));

__device__ __forceinline__ float sspf(float z) {
    // ssp(z) = max(z,0) + log(1+exp(-|z|)) - ln2   (fast HW intrinsics)
    return fmaxf(z, 0.f) + __logf(1.f + __expf(-fabsf(z))) - LN2F;
}

__device__ __forceinline__ half4_t cvt4(float x, float y, float z, float w) {
    half4_t r; r[0] = (half_t)x; r[1] = (half_t)y; r[2] = (half_t)z; r[3] = (half_t)w;
    return r;
}

// dst[n*Kp + k] = (k < K) ? src[k*128 + n] : 0   (f32 -> f16, transpose, K-pad)
__global__ __launch_bounds__(256) void transpose_cvt(
    const float* __restrict__ src, half_t* __restrict__ dst, int K, int Kp)
{
    int i = blockIdx.x * 256 + threadIdx.x;
    if (i >= 128 * Kp) return;
    int n = i / Kp, k = i % Kp;
    dst[i] = (k < K) ? (half_t)src[k * 128 + n] : (half_t)0.f;
}

// atom_start[a] = first edge index with idx_i >= a; atom_start[N] = E
__global__ __launch_bounds__(256) void seg_starts(
    const int* __restrict__ idx_i, int* __restrict__ atom_start, int E, int N)
{
    int e = blockIdx.x * 256 + threadIdx.x;
    if (e >= E) return;
    int a = idx_i[e];
    int prev = (e == 0) ? -1 : idx_i[e - 1];
    for (int k = prev + 1; k <= a; ++k) atom_start[k] = e;
    if (e == E - 1)
        for (int k = a + 1; k <= N; ++k) atom_start[k] = E;
}

// C = act(A @ B + bias); A:[nrows,128] f32, Bt:[128][128] f16 (Bt[n][k]=B[k][n])
__global__ __launch_bounds__(256) void mfma_gemm(
    const float* __restrict__ A, const half_t* __restrict__ Bt,
    const float* __restrict__ bias, float* __restrict__ C,
    int nrows, int act)
{
    const int tid = threadIdx.x;
    const int w = tid >> 6, l = tid & 63, g = l >> 4, ln = l & 15;
    const int r0 = blockIdx.x * 64;

    f32x4 acc[4][2];
    #pragma unroll
    for (int rf = 0; rf < 4; ++rf)
        #pragma unroll
        for (int cf = 0; cf < 2; ++cf) acc[rf][cf] = (f32x4)0.f;

    #pragma unroll
    for (int kk = 0; kk < 8; ++kk) {
        const int kb = kk * 16 + g * 4;
        half4_t a[4];
        #pragma unroll
        for (int rf = 0; rf < 4; ++rf) {
            int r = r0 + rf * 16 + ln;
            int rr = r < nrows ? r : nrows - 1;
            float4 av = *(const float4*)(A + (size_t)rr * 128 + kb);
            a[rf] = cvt4(av.x, av.y, av.z, av.w);
        }
        #pragma unroll
        for (int cf = 0; cf < 2; ++cf) {
            int n = w * 32 + cf * 16 + ln;
            half4_t b = *(const half4_t*)(Bt + (size_t)n * 128 + kb);
            #pragma unroll
            for (int rf = 0; rf < 4; ++rf)
                acc[rf][cf] = __builtin_amdgcn_mfma_f32_16x16x16f16(a[rf], b, acc[rf][cf], 0, 0, 0);
        }
    }

    #pragma unroll
    for (int cf = 0; cf < 2; ++cf) {
        int n = w * 32 + cf * 16 + ln;
        float bv = bias ? bias[n] : 0.f;
        #pragma unroll
        for (int rf = 0; rf < 4; ++rf) {
            #pragma unroll
            for (int reg = 0; reg < 4; ++reg) {
                int r = r0 + rf * 16 + g * 4 + reg;
                if (r < nrows) {
                    float v = acc[rf][cf][reg] + bv;
                    C[(size_t)r * 128 + n] = act ? sspf(v) : v;
                }
            }
        }
    }
}

// Fused edge pipeline: block = 8 atoms, 512 threads (8 waves, wave owns 16 cols).
// Double-buffered f16 f_ij staging + metadata; h-gathers issued before the
// MFMA phase (latency hidden under 32 MFMAs); W fragments held in registers.
__global__ __launch_bounds__(512, 4) void edge_kernel(
    const float* __restrict__ f_ij, const float* __restrict__ rcut,
    const int* __restrict__ idx_i, const int* __restrict__ idx_j,
    const half_t* __restrict__ Wt_f1, const float* __restrict__ b_f1,
    const half_t* __restrict__ Wt_f2, const float* __restrict__ b_f2,
    const float* __restrict__ h, float* __restrict__ agg,
    const int* __restrict__ atom_start, int E, int N)
{
    __shared__ __align__(16) half_t fsh[2][64][24];   //  6144 B
    __shared__ __align__(16) half_t w1s[64][136];     // 17408 B (pad -> 2-way max)
    __shared__ float bins[AT][128];                   //  4096 B
    __shared__ int   jis[2][64];
    __shared__ int   ais[2][64];
    __shared__ float rcs[2][64];

    const int tid = threadIdx.x;
    const int w = tid >> 6, l = tid & 63, g = l >> 4, ln = l & 15;
    const int n = w * 16 + ln;            // this thread's output column
    const int a0 = blockIdx.x * AT;

    for (int i = tid; i < AT * 128; i += 512) ((float*)bins)[i] = 0.f;

    const int lo = atom_start[a0];
    const int hi = atom_start[min(a0 + AT, N)];

    // persistent B fragments (filter weights) in registers
    half4_t b1f[2], b2f[8];
    #pragma unroll
    for (int kk = 0; kk < 2; ++kk)
        b1f[kk] = *(const half4_t*)(Wt_f1 + (size_t)n * 32 + kk * 16 + g * 4);
    #pragma unroll
    for (int kk = 0; kk < 8; ++kk)
        b2f[kk] = *(const half4_t*)(Wt_f2 + (size_t)n * 128 + kk * 16 + g * 4);
    const float bf1v = b_f1[n];
    const float bf2v = b_f2[n];

    // prologue: stage chunk 0 into buffer 0
    if (lo < hi) {
        if (tid < 320) {
            int e = lo + tid / 5;
            float4 v = (e < E) ? ((const float4*)f_ij)[(size_t)lo * 5 + tid]
                               : make_float4(0.f, 0.f, 0.f, 0.f);
            *(half4_t*)&fsh[0][tid / 5][(tid % 5) * 4] = cvt4(v.x, v.y, v.z, v.w);
        } else if (tid < 384) { int k = tid - 320, e = lo + k; jis[0][k] = (e < E) ? idx_j[e] : 0; }
        else if (tid < 448)   { int k = tid - 384, e = lo + k; ais[0][k] = (e < E) ? idx_i[e] : a0; }
        else                  { int k = tid - 448, e = lo + k; rcs[0][k] = (e < E) ? rcut[e] : 0.f; }
    }

    float run = 0.f; int cur = -1;
    int p = 0;
    for (int c0 = lo; c0 < hi; c0 += 64, p ^= 1) {
        __syncthreads();   // buffers[p] ready; w1s free (phase2 of prev done)

        // stage chunk c+1 into buffer p^1 (loads issued early, hidden under compute)
        int c1 = c0 + 64;
        if (c1 < hi) {
            if (tid < 320) {
                int e = c1 + tid / 5;
                float4 v = (e < E) ? ((const float4*)f_ij)[(size_t)c1 * 5 + tid]
                                   : make_float4(0.f, 0.f, 0.f, 0.f);
                *(half4_t*)&fsh[p ^ 1][tid / 5][(tid % 5) * 4] = cvt4(v.x, v.y, v.z, v.w);
            } else if (tid < 384) { int k = tid - 320, e = c1 + k; jis[p ^ 1][k] = (e < E) ? idx_j[e] : 0; }
            else if (tid < 448)   { int k = tid - 384, e = c1 + k; ais[p ^ 1][k] = (e < E) ? idx_i[e] : a0; }
            else                  { int k = tid - 448, e = c1 + k; rcs[p ^ 1][k] = (e < E) ? rcut[e] : 0.f; }
        }

        // metadata -> regs; ISSUE h-gathers now (consumed after phase 2)
        float hv[16], rc[16]; int ai[16];
        #pragma unroll
        for (int rf = 0; rf < 4; ++rf)
            #pragma unroll
            for (int reg = 0; reg < 4; ++reg) {
                int k = rf * 16 + g * 4 + reg, q = rf * 4 + reg;
                int ji = jis[p][k];
                hv[q] = h[(size_t)ji * 128 + n];
                bool val = (c0 + k) < hi;
                rc[q] = val ? rcs[p][k] : 0.f;
                ai[q] = val ? ais[p][k] : a0;
            }

        // phase 1: z = f_ij @ W1 (K=20 padded to 32)
        f32x4 z[4];
        #pragma unroll
        for (int rf = 0; rf < 4; ++rf) z[rf] = (f32x4)0.f;
        #pragma unroll
        for (int kk = 0; kk < 2; ++kk) {
            const int kb = kk * 16 + g * 4;
            #pragma unroll
            for (int rf = 0; rf < 4; ++rf) {
                half4_t a = (half4_t)(half_t)0.f;
                if (kb < 20) a = *(const half4_t*)&fsh[p][rf * 16 + ln][kb];
                z[rf] = __builtin_amdgcn_mfma_f32_16x16x16f16(a, b1f[kk], z[rf], 0, 0, 0);
            }
        }
        // w1 = ssp(z + b1) -> LDS
        #pragma unroll
        for (int rf = 0; rf < 4; ++rf)
            #pragma unroll
            for (int reg = 0; reg < 4; ++reg)
                w1s[rf * 16 + g * 4 + reg][n] = (half_t)sspf(z[rf][reg] + bf1v);
        __syncthreads();

        // phase 2: acc = w1 @ W2 (K=128), hides the h-gather latency
        f32x4 acc[4];
        #pragma unroll
        for (int rf = 0; rf < 4; ++rf) acc[rf] = (f32x4)0.f;
        #pragma unroll
        for (int kk = 0; kk < 8; ++kk) {
            const int kb = kk * 16 + g * 4;
            #pragma unroll
            for (int rf = 0; rf < 4; ++rf) {
                half4_t a = *(const half4_t*)&w1s[rf * 16 + ln][kb];
                acc[rf] = __builtin_amdgcn_mfma_f32_16x16x16f16(a, b2f[kk], acc[rf], 0, 0, 0);
            }
        }

        // epilogue: (+b2)*rcut*h, run-merged LDS binning (no global atomics)
        #pragma unroll
        for (int rf = 0; rf < 4; ++rf)
            #pragma unroll
            for (int reg = 0; reg < 4; ++reg) {
                int q = rf * 4 + reg;
                float v = (acc[rf][reg] + bf2v) * rc[q] * hv[q];
                if (ai[q] != cur) {
                    if (cur >= 0) atomicAdd(&bins[cur - a0][n], run);
                    cur = ai[q]; run = v;
                } else run += v;
            }
    }
    if (cur >= 0) atomicAdd(&bins[cur - a0][n], run);
    __syncthreads();

    for (int i = tid; i < AT * 128; i += 512) {
        int at = i >> 7, c = i & 127;
        int arow = a0 + at;
        if (arow < N) agg[(size_t)arow * 128 + c] = bins[at][c];
    }
}

extern "C" void kernel_launch(void* const* d_in, const int* in_sizes, int n_in,
                              void* d_out, int out_size, void* d_ws, size_t ws_size,
                              hipStream_t stream)
{
    const float* x      = (const float*)d_in[0];
    const float* f_ij   = (const float*)d_in[1];
    const float* rcut   = (const float*)d_in[2];
    const int*   idx_i  = (const int*)d_in[3];
    const int*   idx_j  = (const int*)d_in[4];
    const float* W_in2f = (const float*)d_in[5];
    const float* W_f1   = (const float*)d_in[6];
    const float* b_f1   = (const float*)d_in[7];
    const float* W_f2   = (const float*)d_in[8];
    const float* b_f2   = (const float*)d_in[9];
    const float* W_o1   = (const float*)d_in[10];
    const float* b_o1   = (const float*)d_in[11];
    const float* W_o2   = (const float*)d_in[12];
    const float* b_o2   = (const float*)d_in[13];

    const int N = in_sizes[0] / 128;
    const int E = in_sizes[2];

    float*  hbuf = (float*)d_ws;                         // [N,128] f32; reused as t
    half_t* wt   = (half_t*)((char*)d_ws + (size_t)N * 128 * 4);
    half_t* Wt_in2f = wt;                 // 128*128
    half_t* Wt_f1   = wt + 16384;         // 128*32 (K padded 20->32)
    half_t* Wt_f2   = wt + 16384 + 4096;  // 128*128
    half_t* Wt_o1   = Wt_f2 + 16384;      // 128*128
    half_t* Wt_o2   = Wt_o1 + 16384;      // 128*128
    int* atom_start = (int*)(Wt_o2 + 16384);             // N+1 ints

    // weight prep: f32 -> f16 transposed Bt[n][k]
    transpose_cvt<<<64, 256, 0, stream>>>(W_in2f, Wt_in2f, 128, 128);
    transpose_cvt<<<16, 256, 0, stream>>>(W_f1,   Wt_f1,    20,  32);
    transpose_cvt<<<64, 256, 0, stream>>>(W_f2,   Wt_f2,   128, 128);
    transpose_cvt<<<64, 256, 0, stream>>>(W_o1,   Wt_o1,   128, 128);
    transpose_cvt<<<64, 256, 0, stream>>>(W_o2,   Wt_o2,   128, 128);

    // segment starts for sorted idx_i
    seg_starts<<<(E + 255) / 256, 256, 0, stream>>>(idx_i, atom_start, E, N);

    const int gn = (N + 63) / 64;
    const int ga = (N + AT - 1) / AT;

    // h = x @ W_in2f
    mfma_gemm<<<gn, 256, 0, stream>>>(x, Wt_in2f, nullptr, hbuf, N, 0);

    // fused edge pipeline -> agg (full overwrite of d_out rows)
    edge_kernel<<<ga, 512, 0, stream>>>(f_ij, rcut, idx_i, idx_j,
                                        Wt_f1, b_f1, Wt_f2, b_f2,
                                        hbuf, (float*)d_out, atom_start, E, N);

    // t = ssp(agg @ W_o1 + b_o1)
    mfma_gemm<<<gn, 256, 0, stream>>>((const float*)d_out, Wt_o1, b_o1, hbuf, N, 1);

    // out = t @ W_o2 + b_o2
    mfma_gemm<<<gn, 256, 0, stream>>>(hbuf, Wt_o2, b_o2, (float*)d_out, N, 0);
}